// Round 7
// baseline (143.284 us; speedup 1.0000x reference)
//
#include <hip/hip_runtime.h>
#include <hip/hip_bf16.h>

// B=16,S=4096,H=512 ; G=2,V=320,D=256 (Dg=128)
constexpr int BT = 65536;
constexpr int K  = 512;
constexpr int V  = 320;
constexpr int G  = 2;
constexpr int Dg = 128;
constexpr int MT = 128;          // rows per block (8 waves: 2 row-halves x 4 col-quarters)
constexpr int NSTEP = 16;        // K/32
constexpr int BUFB  = 28672;     // per-buffer LDS: A bf16 [128][32] 8KB @0, B img 20KB @8192
constexpr size_t WS_IMG = 4096;  // ws: [0,2560) hist ; swizzled B img @4096 (640 KB)

using short8 = __attribute__((ext_vector_type(8))) short;
using f32x4  = __attribute__((ext_vector_type(4))) float;

static __device__ __forceinline__ unsigned short f2bf(float x) {
    unsigned u = __float_as_uint(x);
    unsigned r = 0x7FFFu + ((u >> 16) & 1u);   // RNE
    return (unsigned short)((u + r) >> 16);
}
static __device__ __forceinline__ unsigned pk2(float a, float b) {
    return (unsigned)f2bf(a) | ((unsigned)f2bf(b) << 16);
}
static __device__ __forceinline__ f32x4 mfma16(short8 a, short8 b, f32x4 c) {
    return __builtin_amdgcn_mfma_f32_16x16x32_bf16(a, b, c, 0, 0, 0);
}

// ---- prep: swizzled LDS byte-images of the Bh panels (proven clean in R5) ----
// img[(g*16+t)*20480 + ((c*64+q*16) ^ (((c>>1)&7)<<4))] = bf16x8 of W[t*32+q*8..+7][g*320+c]
__global__ __launch_bounds__(256) void vq_prep(const float* __restrict__ Wm,
                                               unsigned char* __restrict__ img)
{
    int id = blockIdx.x * 256 + threadIdx.x;   // 160*256 = 40960 chunks exact
    int q  = id & 3;
    int c  = (id >> 2) % V;
    int tk = (id >> 2) / V;                    // g*16 + t
    int g  = tk >> 4;
    int t  = tk & 15;
    int kb = t * 32 + q * 8;
    unsigned p[4];
#pragma unroll
    for (int jj = 0; jj < 4; ++jj)
        p[jj] = pk2(Wm[(size_t)(kb + 2 * jj) * 640 + g * V + c],
                    Wm[(size_t)(kb + 2 * jj + 1) * 640 + g * V + c]);
    *reinterpret_cast<uint4*>(img + (size_t)tk * 20480 +
        ((c * 64 + q * 16) ^ (((c >> 1) & 7) << 4))) = make_uint4(p[0], p[1], p[2], p[3]);
}

// ---- main: bf16 MFMA GEMM (128x320x512), B via global_load_lds dbuf, counted vmcnt ----
// grid 1024: g=(bid>>3)&1, rblk=(bid&7)|((bid>>4)<<3)  (bid,bid+8 same XCD share hs panel)
__global__ __launch_bounds__(512, 4) void vq_main(
    const float* __restrict__ hs, const unsigned char* __restrict__ img,
    const float* __restrict__ bv, const float* __restrict__ cbv,
    float* __restrict__ out, unsigned int* __restrict__ hist)
{
    __shared__ __align__(16) unsigned char smem[2 * BUFB];   // 56 KB -> 2 blocks/CU

    const int tid  = threadIdx.x;
    const int bid  = blockIdx.x;
    const int g    = (bid >> 3) & 1;
    const int rblk = (bid & 7) | ((bid >> 4) << 3);
    const int r0   = rblk * MT;
    const int w    = tid >> 6;      // wave 0..7
    const int lane = tid & 63;
    const int l4   = lane & 15;
    const int lc   = lane >> 4;
    const int wc   = w & 3;         // col quarter (80 cols)
    const int h    = w >> 2;        // row half (64 rows)

    f32x4 acc[4][5] = {};

    // fragment read offsets (swizzles verified conflict-free: each 16-lane phase = 32 banks x2)
    const int a_base = h * 4096 + ((l4 * 64 + lc * 16) ^ (((l4 >> 1) & 3) << 4));
    const int b_base = 8192 + wc * 5120 + ((l4 * 64 + lc * 16) ^ (((l4 >> 1) & 7) << 4));

    // A staging: thread -> row tid>>2, k-quad tid&3 (8 floats -> 8 bf16 = one b128 write)
    const int arow = tid >> 2, akq = tid & 3;
    const float* aptr = hs + (size_t)(r0 + arow) * K + akq * 8;
    const int awoff = (arow * 64 + akq * 16) ^ (((arow >> 1) & 3) << 4);
    // B staging source (per-lane addr = linear chunk stream; dest wave-uniform)
    const unsigned char* bpan0 = img + (size_t)(g * 16) * 20480 + (size_t)tid * 16;

    auto stageB = [&](int t, int bufoff) {
        const unsigned char* s = bpan0 + (size_t)t * 20480;
        __builtin_amdgcn_global_load_lds(
            (const __attribute__((address_space(1))) void*)(s),
            (__attribute__((address_space(3))) void*)(&smem[bufoff + 8192 + w * 1024]), 16, 0, 0);
        __builtin_amdgcn_global_load_lds(
            (const __attribute__((address_space(1))) void*)(s + 8192),
            (__attribute__((address_space(3))) void*)(&smem[bufoff + 16384 + w * 1024]), 16, 0, 0);
        if (tid < 256)   // wave-uniform: waves 0-3 carry the 3rd chunk batch
            __builtin_amdgcn_global_load_lds(
                (const __attribute__((address_space(1))) void*)(s + 16384),
                (__attribute__((address_space(3))) void*)(&smem[bufoff + 24576 + w * 1024]), 16, 0, 0);
    };
    auto packA = [&](float4 x, float4 y, int bufoff) {
        *reinterpret_cast<uint4*>(&smem[bufoff + awoff]) =
            make_uint4(pk2(x.x, x.y), pk2(x.z, x.w), pk2(y.x, y.y), pk2(y.z, y.w));
    };

    // ---- prologue ----
    float4 pax = *reinterpret_cast<const float4*>(aptr);        // A(0)
    float4 pay = *reinterpret_cast<const float4*>(aptr + 4);
    stageB(0, 0);
    __builtin_amdgcn_sched_barrier(0);                          // pin B(0) before A(1) issue
    float4 nax = *reinterpret_cast<const float4*>(aptr + 32);   // A(1) in flight
    float4 nay = *reinterpret_cast<const float4*>(aptr + 36);
    packA(pax, pay, 0);                                         // compiler waits A(0) only
    asm volatile("s_waitcnt vmcnt(2) lgkmcnt(0)" ::: "memory"); // drain B(0)+write; keep A(1)
    __builtin_amdgcn_s_barrier();

#pragma unroll
    for (int t = 0; t < NSTEP; ++t) {
        const int co = (t & 1) * BUFB, no = co ^ BUFB;
        if (t + 1 < NSTEP) stageB(t + 1, no);         // async into next buffer
        __builtin_amdgcn_sched_barrier(0);            // keep B-issue before A-issue (vmcnt count)
        float4 fax, fay;
        if (t + 2 < NSTEP) {
            fax = *reinterpret_cast<const float4*>(aptr + (t + 2) * 32);
            fay = *reinterpret_cast<const float4*>(aptr + (t + 2) * 32 + 4);
        }
        // compute tile t: 4 + 5 ds_read_b128 (compiler-inserted lgkmcnt), 20 MFMA
        short8 av[4];
#pragma unroll
        for (int mt = 0; mt < 4; ++mt)
            av[mt] = *reinterpret_cast<const short8*>(&smem[co + a_base + mt * 1024]);
#pragma unroll
        for (int nt = 0; nt < 5; ++nt) {
            short8 bb = *reinterpret_cast<const short8*>(&smem[co + b_base + nt * 1024]);
#pragma unroll
            for (int mt = 0; mt < 4; ++mt) acc[mt][nt] = mfma16(av[mt], bb, acc[mt][nt]);
        }
        if (t + 1 < NSTEP) packA(nax, nay, no);       // consumes A(t+1), loaded last step
        if (t + 2 < NSTEP) { nax = fax; nay = fay; }
        if (t + 2 < NSTEP)
            asm volatile("s_waitcnt vmcnt(2) lgkmcnt(0)" ::: "memory");  // drain B(t+1); keep A(t+2)
        else
            asm volatile("s_waitcnt vmcnt(0) lgkmcnt(0)" ::: "memory");  // tail: drain all
        __builtin_amdgcn_s_barrier();
    }

    // ---- epilogue: bias + argmax (D: col=l4, row=lc*4+reg within 16x16 tile) ----
    float biasv[5];
#pragma unroll
    for (int nt = 0; nt < 5; ++nt) biasv[nt] = bv[g * V + wc * 80 + nt * 16 + l4];

    float* red_v = reinterpret_cast<float*>(smem);          // [128][4]
    int*   red_i = reinterpret_cast<int*>(smem + 2048);     // [128][4]
    int*   idx_s = reinterpret_cast<int*>(smem + 4096);     // [128]

#pragma unroll
    for (int mt = 0; mt < 4; ++mt) {
#pragma unroll
        for (int reg = 0; reg < 4; ++reg) {
            float bestv = acc[mt][0][reg] + biasv[0];
            int   besti = wc * 80 + l4;
#pragma unroll
            for (int nt = 1; nt < 5; ++nt) {
                float v = acc[mt][nt][reg] + biasv[nt];
                int   ci = wc * 80 + nt * 16 + l4;
                if (v > bestv) { bestv = v; besti = ci; }
            }
#pragma unroll
            for (int m = 1; m < 16; m <<= 1) {   // reduce across the 16 l4-lanes of this row
                float ov = __shfl_xor(bestv, m);
                int   oi = __shfl_xor(besti, m);
                if (ov > bestv || (ov == bestv && oi < besti)) { bestv = ov; besti = oi; }
            }
            if (l4 == 0) {
                int row = h * 64 + mt * 16 + lc * 4 + reg;
                red_v[row * 4 + wc] = bestv;
                red_i[row * 4 + wc] = besti;
            }
        }
    }
    __syncthreads();

    if (tid < MT) {
        float bb = red_v[tid * 4]; int bi = red_i[tid * 4];
#pragma unroll
        for (int c = 1; c < 4; ++c) {
            float v = red_v[tid * 4 + c]; int ii = red_i[tid * 4 + c];
            if (v > bb || (v == bb && ii < bi)) { bb = v; bi = ii; }
        }
        idx_s[tid] = bi;
        atomicAdd(&hist[g * V + bi], 1u);
    }
    __syncthreads();

    // ---- gather: 128 rows x 32 float4 = 4096 chunks, 8 per thread ----
#pragma unroll
    for (int i = 0; i < 8; ++i) {
        int idx = i * 512 + tid;
        int row = idx >> 5;
        int d4  = idx & 31;
        int vi  = idx_s[row];
        float4 val = *reinterpret_cast<const float4*>(&cbv[((size_t)(g * V + vi)) * Dg + d4 * 4]);
        *reinterpret_cast<float4*>(&out[((size_t)(r0 + row)) * (G * Dg) + g * Dg + d4 * 4]) = val;
    }
}

// Perplexity from histogram: one wave.
__global__ void vq_ppl(const unsigned int* __restrict__ hist, float* __restrict__ outp)
{
    int lane = threadIdx.x;  // 64
    float ppl = 0.0f;
    for (int g = 0; g < G; ++g) {
        float local = 0.0f;
        for (int v = lane; v < V; v += 64) {
            float m = (float)hist[g * V + v] * (1.0f / (float)BT);
            local += m * logf(m + 1e-7f);
        }
#pragma unroll
        for (int off = 32; off; off >>= 1) local += __shfl_down(local, off);
        if (lane == 0) ppl += expf(-local);
    }
    if (lane == 0) outp[0] = ppl;
}

extern "C" void kernel_launch(void* const* d_in, const int* in_sizes, int n_in,
                              void* d_out, int out_size, void* d_ws, size_t ws_size,
                              hipStream_t stream)
{
    const float* hs  = (const float*)d_in[0];   // (65536, 512)
    const float* Wm  = (const float*)d_in[1];   // (512, 640)
    const float* bv  = (const float*)d_in[2];   // (640,)
    const float* cbv = (const float*)d_in[3];   // (640, 128)
    float* out = (float*)d_out;                 // 65536*256 floats + 1 float perplexity

    unsigned int*  hist = (unsigned int*)d_ws;
    unsigned char* img  = (unsigned char*)d_ws + WS_IMG;

    hipMemsetAsync(d_ws, 0, G * V * sizeof(unsigned int), stream);
    vq_prep<<<160, 256, 0, stream>>>(Wm, img);
    vq_main<<<1024, 512, 0, stream>>>(hs, img, bv, cbv, out, hist);
    vq_ppl<<<1, 64, 0, stream>>>(hist, out + (size_t)BT * G * Dg);
}

// Round 8
// 114.761 us; speedup vs baseline: 1.2485x; 1.2485x over previous
//
#include <hip/hip_runtime.h>
#include <hip/hip_bf16.h>

// B=16,S=4096,H=512 ; G=2,V=320,D=256 (Dg=128)
constexpr int BT = 65536;
constexpr int K  = 512;
constexpr int V  = 320;
constexpr int G  = 2;
constexpr int Dg = 128;
constexpr int MT = 128;          // rows per block (8 waves: 2 row-halves x 4 col-quarters)
constexpr int NSTEP = 16;        // K/32
constexpr int BUFB  = 28672;     // per-buffer LDS: A bf16 [128][32] 8KB @0, B img 20KB @8192
constexpr size_t WS_IMG = 4096;  // ws: [0,2560) hist ; swizzled B img @4096 (640 KB)

using short8 = __attribute__((ext_vector_type(8))) short;
using f32x4  = __attribute__((ext_vector_type(4))) float;

static __device__ __forceinline__ unsigned short f2bf(float x) {
    unsigned u = __float_as_uint(x);
    unsigned r = 0x7FFFu + ((u >> 16) & 1u);   // RNE
    return (unsigned short)((u + r) >> 16);
}
static __device__ __forceinline__ unsigned pk2(float a, float b) {
    return (unsigned)f2bf(a) | ((unsigned)f2bf(b) << 16);
}
static __device__ __forceinline__ f32x4 mfma16(short8 a, short8 b, f32x4 c) {
    return __builtin_amdgcn_mfma_f32_16x16x32_bf16(a, b, c, 0, 0, 0);
}

// ---- prep: swizzled LDS byte-images of the Bh panels (proven clean in R5) ----
// img[(g*16+t)*20480 + ((c*64+q*16) ^ (((c>>1)&7)<<4))] = bf16x8 of W[t*32+q*8..+7][g*320+c]
__global__ __launch_bounds__(256) void vq_prep(const float* __restrict__ Wm,
                                               unsigned char* __restrict__ img)
{
    int id = blockIdx.x * 256 + threadIdx.x;   // 160*256 = 40960 chunks exact
    int q  = id & 3;
    int c  = (id >> 2) % V;
    int tk = (id >> 2) / V;                    // g*16 + t
    int g  = tk >> 4;
    int t  = tk & 15;
    int kb = t * 32 + q * 8;
    unsigned p[4];
#pragma unroll
    for (int jj = 0; jj < 4; ++jj)
        p[jj] = pk2(Wm[(size_t)(kb + 2 * jj) * 640 + g * V + c],
                    Wm[(size_t)(kb + 2 * jj + 1) * 640 + g * V + c]);
    *reinterpret_cast<uint4*>(img + (size_t)tk * 20480 +
        ((c * 64 + q * 16) ^ (((c >> 1) & 7) << 4))) = make_uint4(p[0], p[1], p[2], p[3]);
}

// ---- main: bf16 MFMA GEMM (128x320x512), B via global_load_lds dbuf, counted vmcnt ----
// grid 1024: g=(bid>>3)&1, rblk=(bid&7)|((bid>>4)<<3)  (bid,bid+8 same XCD share hs panel)
// NOTE: no launch_bounds min-occupancy arg — R2 and R7 both showed arg=4 => 64-VGPR clamp
// => 80-reg accumulator spills to scratch (FETCH +56MB). LDS pins 2 blocks/CU anyway.
__global__ __launch_bounds__(512) void vq_main(
    const float* __restrict__ hs, const unsigned char* __restrict__ img,
    const float* __restrict__ bv, const float* __restrict__ cbv,
    float* __restrict__ out, unsigned int* __restrict__ hist)
{
    __shared__ __align__(16) unsigned char smem[2 * BUFB];   // 56 KB -> 2 blocks/CU

    const int tid  = threadIdx.x;
    const int bid  = blockIdx.x;
    const int g    = (bid >> 3) & 1;
    const int rblk = (bid & 7) | ((bid >> 4) << 3);
    const int r0   = rblk * MT;
    const int w    = tid >> 6;      // wave 0..7
    const int lane = tid & 63;
    const int l4   = lane & 15;
    const int lc   = lane >> 4;
    const int wc   = w & 3;         // col quarter (80 cols)
    const int h    = w >> 2;        // row half (64 rows)

    f32x4 acc[4][5] = {};

    // fragment read offsets (swizzles verified conflict-free in R5/R7: 75K total conflicts)
    const int a_base = h * 4096 + ((l4 * 64 + lc * 16) ^ (((l4 >> 1) & 3) << 4));
    const int b_base = 8192 + wc * 5120 + ((l4 * 64 + lc * 16) ^ (((l4 >> 1) & 7) << 4));

    // A staging: thread -> row tid>>2, k-quad tid&3 (8 floats -> 8 bf16 = one b128 write)
    const int arow = tid >> 2, akq = tid & 3;
    const float* aptr = hs + (size_t)(r0 + arow) * K + akq * 8;
    const int awoff = (arow * 64 + akq * 16) ^ (((arow >> 1) & 3) << 4);
    // B staging source (per-lane addr = linear chunk stream; dest wave-uniform)
    const unsigned char* bpan0 = img + (size_t)(g * 16) * 20480 + (size_t)tid * 16;

    auto stageB = [&](int t, int bufoff) {
        const unsigned char* s = bpan0 + (size_t)t * 20480;
        __builtin_amdgcn_global_load_lds(
            (const __attribute__((address_space(1))) void*)(s),
            (__attribute__((address_space(3))) void*)(&smem[bufoff + 8192 + w * 1024]), 16, 0, 0);
        __builtin_amdgcn_global_load_lds(
            (const __attribute__((address_space(1))) void*)(s + 8192),
            (__attribute__((address_space(3))) void*)(&smem[bufoff + 16384 + w * 1024]), 16, 0, 0);
        if (tid < 256)   // wave-uniform branch: waves 0-3 carry the 3rd chunk batch
            __builtin_amdgcn_global_load_lds(
                (const __attribute__((address_space(1))) void*)(s + 16384),
                (__attribute__((address_space(3))) void*)(&smem[bufoff + 24576 + w * 1024]), 16, 0, 0);
    };
    auto packA = [&](float4 x, float4 y, int bufoff) {
        *reinterpret_cast<uint4*>(&smem[bufoff + awoff]) =
            make_uint4(pk2(x.x, x.y), pk2(x.z, x.w), pk2(y.x, y.y), pk2(y.z, y.w));
    };

    // ---- prologue ----
    float4 pax = *reinterpret_cast<const float4*>(aptr);        // A(0)
    float4 pay = *reinterpret_cast<const float4*>(aptr + 4);
    stageB(0, 0);
    __builtin_amdgcn_sched_barrier(0);                          // pin B(0) before A(1) issue
    float4 nax = *reinterpret_cast<const float4*>(aptr + 32);   // A(1) in flight
    float4 nay = *reinterpret_cast<const float4*>(aptr + 36);
    packA(pax, pay, 0);                                         // compiler waits A(0) only
    asm volatile("s_waitcnt vmcnt(2) lgkmcnt(0)" ::: "memory"); // drain B(0)+write; keep A(1)
    __builtin_amdgcn_s_barrier();

#pragma unroll
    for (int t = 0; t < NSTEP; ++t) {
        const int co = (t & 1) * BUFB, no = co ^ BUFB;
        if (t + 1 < NSTEP) stageB(t + 1, no);         // async into next buffer
        __builtin_amdgcn_sched_barrier(0);            // keep B-issue before A-issue (vmcnt count)
        float4 fax, fay;
        if (t + 2 < NSTEP) {
            fax = *reinterpret_cast<const float4*>(aptr + (t + 2) * 32);
            fay = *reinterpret_cast<const float4*>(aptr + (t + 2) * 32 + 4);
        }
        // compute tile t: 4 + 5 ds_read_b128 (compiler-inserted lgkmcnt), 20 MFMA
        short8 av[4];
#pragma unroll
        for (int mt = 0; mt < 4; ++mt)
            av[mt] = *reinterpret_cast<const short8*>(&smem[co + a_base + mt * 1024]);
#pragma unroll
        for (int nt = 0; nt < 5; ++nt) {
            short8 bb = *reinterpret_cast<const short8*>(&smem[co + b_base + nt * 1024]);
#pragma unroll
            for (int mt = 0; mt < 4; ++mt) acc[mt][nt] = mfma16(av[mt], bb, acc[mt][nt]);
        }
        if (t + 1 < NSTEP) packA(nax, nay, no);       // consumes A(t+1), loaded last step
        if (t + 2 < NSTEP) { nax = fax; nay = fay; }
        if (t + 2 < NSTEP)
            asm volatile("s_waitcnt vmcnt(2) lgkmcnt(0)" ::: "memory");  // drain B(t+1); keep A(t+2)
        else
            asm volatile("s_waitcnt vmcnt(0) lgkmcnt(0)" ::: "memory");  // tail: drain all
        __builtin_amdgcn_s_barrier();
    }

    // ---- epilogue: bias + argmax (D: col=l4, row=lc*4+reg within 16x16 tile) ----
    float biasv[5];
#pragma unroll
    for (int nt = 0; nt < 5; ++nt) biasv[nt] = bv[g * V + wc * 80 + nt * 16 + l4];

    float* red_v = reinterpret_cast<float*>(smem);          // [128][4]
    int*   red_i = reinterpret_cast<int*>(smem + 2048);     // [128][4]
    int*   idx_s = reinterpret_cast<int*>(smem + 4096);     // [128]

#pragma unroll
    for (int mt = 0; mt < 4; ++mt) {
#pragma unroll
        for (int reg = 0; reg < 4; ++reg) {
            float bestv = acc[mt][0][reg] + biasv[0];
            int   besti = wc * 80 + l4;
#pragma unroll
            for (int nt = 1; nt < 5; ++nt) {
                float v = acc[mt][nt][reg] + biasv[nt];
                int   ci = wc * 80 + nt * 16 + l4;
                if (v > bestv) { bestv = v; besti = ci; }
            }
#pragma unroll
            for (int m = 1; m < 16; m <<= 1) {   // reduce across the 16 l4-lanes of this row
                float ov = __shfl_xor(bestv, m);
                int   oi = __shfl_xor(besti, m);
                if (ov > bestv || (ov == bestv && oi < besti)) { bestv = ov; besti = oi; }
            }
            if (l4 == 0) {
                int row = h * 64 + mt * 16 + lc * 4 + reg;
                red_v[row * 4 + wc] = bestv;
                red_i[row * 4 + wc] = besti;
            }
        }
    }
    __syncthreads();

    if (tid < MT) {
        float bb = red_v[tid * 4]; int bi = red_i[tid * 4];
#pragma unroll
        for (int c = 1; c < 4; ++c) {
            float v = red_v[tid * 4 + c]; int ii = red_i[tid * 4 + c];
            if (v > bb || (v == bb && ii < bi)) { bb = v; bi = ii; }
        }
        idx_s[tid] = bi;
        atomicAdd(&hist[g * V + bi], 1u);
    }
    __syncthreads();

    // ---- gather: 128 rows x 32 float4 = 4096 chunks, 8 per thread ----
#pragma unroll
    for (int i = 0; i < 8; ++i) {
        int idx = i * 512 + tid;
        int row = idx >> 5;
        int d4  = idx & 31;
        int vi  = idx_s[row];
        float4 val = *reinterpret_cast<const float4*>(&cbv[((size_t)(g * V + vi)) * Dg + d4 * 4]);
        *reinterpret_cast<float4*>(&out[((size_t)(r0 + row)) * (G * Dg) + g * Dg + d4 * 4]) = val;
    }
}

// Perplexity from histogram: one wave.
__global__ void vq_ppl(const unsigned int* __restrict__ hist, float* __restrict__ outp)
{
    int lane = threadIdx.x;  // 64
    float ppl = 0.0f;
    for (int g = 0; g < G; ++g) {
        float local = 0.0f;
        for (int v = lane; v < V; v += 64) {
            float m = (float)hist[g * V + v] * (1.0f / (float)BT);
            local += m * logf(m + 1e-7f);
        }
#pragma unroll
        for (int off = 32; off; off >>= 1) local += __shfl_down(local, off);
        if (lane == 0) ppl += expf(-local);
    }
    if (lane == 0) outp[0] = ppl;
}

extern "C" void kernel_launch(void* const* d_in, const int* in_sizes, int n_in,
                              void* d_out, int out_size, void* d_ws, size_t ws_size,
                              hipStream_t stream)
{
    const float* hs  = (const float*)d_in[0];   // (65536, 512)
    const float* Wm  = (const float*)d_in[1];   // (512, 640)
    const float* bv  = (const float*)d_in[2];   // (640,)
    const float* cbv = (const float*)d_in[3];   // (640, 128)
    float* out = (float*)d_out;                 // 65536*256 floats + 1 float perplexity

    unsigned int*  hist = (unsigned int*)d_ws;
    unsigned char* img  = (unsigned char*)d_ws + WS_IMG;

    hipMemsetAsync(d_ws, 0, G * V * sizeof(unsigned int), stream);
    vq_prep<<<160, 256, 0, stream>>>(Wm, img);
    vq_main<<<1024, 512, 0, stream>>>(hs, img, bv, cbv, out, hist);
    vq_ppl<<<1, 64, 0, stream>>>(hist, out + (size_t)BT * G * Dg);
}